// Round 12
// baseline (189.873 us; speedup 1.0000x reference)
//
#include <hip/hip_runtime.h>
#include <hip/hip_bf16.h>
#include <cstdint>
#include <cstddef>

#define N_NODES 50000
#define DEG     24
#define NEDGE   (N_NODES*DEG)
#define RSZ     500
#define NDIM    64
#define FEATD   192
#define NTILES  (N_NODES/16)     // 3125

// LDS row stride (shorts) for the 16x200 per-wave transpose buffer in k_gate.
#define LSTR    200

// XCD-aligned chunking: all producers/consumers of fin*/pedge use block->XCD
// round-robin (b%8) with contiguous per-XCD data chunks of 6272 nodes.
#define LGRID   1568
#define LCHUNK  196     // k_layer: 196 blocks/XCD x 32 nodes = 6272 nodes
#define TGRID   3136
#define TCHUNK  392     // prep-tanh: 392 blocks/XCD x 16 nodes = 6272 nodes
#define GGRID   784
#define GCHUNK  98      // k_gate: 98 blocks/XCD x 4 tiles x 16 rows = 6272 nodes

// s_waitcnt immediate: lgkmcnt(0) ONLY (vmcnt=63 unconstrained, expcnt=7).
// __threadfence_block() would drain vmcnt(0) too, flushing all global
// prefetches 3x per wave — the invariant pin across six k_gate variants.
#define WAIT_LGKM0() __builtin_amdgcn_s_waitcnt(0xC07F)

typedef short bf16x8 __attribute__((ext_vector_type(8)));
typedef float f32x4  __attribute__((ext_vector_type(4)));

__device__ __forceinline__ unsigned short f2bf(float f) {
    unsigned u = __builtin_bit_cast(unsigned, f);
    unsigned r = (u + 0x7fffu + ((u >> 16) & 1u)) >> 16;   // RNE
    return (unsigned short)r;
}
__device__ __forceinline__ float bf2f(unsigned short s) {
    unsigned u = ((unsigned)s) << 16;
    return __builtin_bit_cast(float, u);
}
__device__ __forceinline__ float lo16(unsigned u) {
    return __builtin_bit_cast(float, u << 16);
}
__device__ __forceinline__ float hi16(unsigned u) {
    return __builtin_bit_cast(float, u & 0xFFFF0000u);
}
__device__ __forceinline__ float fast_tanh(float x) {
    float e = __expf(2.f * x);
    return 1.f - 2.f / (e + 1.f);
}

// ---- PREP (fused): tanh->fin0 (XCD-aligned) | rel(bf16)+expdot | pninv |
//      packB | packE. Ranges: [0,3136) tanh, [3136,3261) rel, [3261,3277)
//      pninv, [3277,3517) packB, [3517,4693) packE.
__global__ __launch_bounds__(256) void k_prep(const float* __restrict__ features,
                                              const float* __restrict__ rel_emb,
                                              const float* __restrict__ attn_k,
                                              const float* __restrict__ proxy,
                                              const float* __restrict__ gate_w,
                                              const int* __restrict__ src,
                                              const int* __restrict__ rel,
                                              unsigned short* __restrict__ fin0,
                                              unsigned short* __restrict__ relnb,
                                              float* __restrict__ expdot,
                                              float* __restrict__ pninv,
                                              unsigned short* __restrict__ B1,
                                              unsigned short* __restrict__ B2,
                                              unsigned short* __restrict__ B3,
                                              unsigned int* __restrict__ pedge) {
    int b = blockIdx.x;
    if (b < TGRID) {
        // tanh -> fin0, XCD-aligned: XCD x writes nodes [x*6272,(x+1)*6272)
        int lb = (b & 7) * TCHUNK + (b >> 3);      // 0..3135
        int idx4 = (lb * 256 + threadIdx.x) * 4;   // 16 nodes/block
        if (idx4 < N_NODES * 64) {
            float4 f = *reinterpret_cast<const float4*>(features + idx4);
            uint2 w;
            w.x = (unsigned)f2bf(fast_tanh(f.x)) | ((unsigned)f2bf(fast_tanh(f.y)) << 16);
            w.y = (unsigned)f2bf(fast_tanh(f.z)) | ((unsigned)f2bf(fast_tanh(f.w)) << 16);
            *reinterpret_cast<uint2*>(fin0 + idx4) = w;
        }
    } else if (b < 3261) {
        int lane = threadIdx.x & 63;
        int row = (b - TGRID) * 4 + (threadIdx.x >> 6);   // 500 rows
        float v = rel_emb[row * 64 + lane];
        float ss = v * v;
        for (int m = 1; m < 64; m <<= 1) ss += __shfl_xor(ss, m);
        float inv = 1.f / fmaxf(sqrtf(ss), 1e-12f);
        float rn = v * inv;
        relnb[row * 64 + lane] = f2bf(rn);
        float d0 = rn * attn_k[lane];
        float d1 = rn * attn_k[64 + lane];
        for (int m = 1; m < 64; m <<= 1) { d0 += __shfl_xor(d0, m); d1 += __shfl_xor(d1, m); }
        if (lane == 0) { expdot[row] = __expf(d0); expdot[RSZ + row] = __expf(d1); }
    } else if (b < 3277) {
        int lane = threadIdx.x & 63;
        int row = (b - 3261) * 4 + (threadIdx.x >> 6);   // 64 rows
        const float* p = proxy + (size_t)row * FEATD;
        float a = p[lane], bb = p[64 + lane], c = p[128 + lane];
        float ss = a * a + bb * bb + c * c;
        for (int m = 1; m < 64; m <<= 1) ss += __shfl_xor(ss, m);
        if (lane == 0) pninv[row] = 1.f / fmaxf(sqrtf(ss), 1e-12f);
    } else if (b < 3517) {
        // B-frag for 16x16x32: lane holds B[k=(lane>>4)*8+j][n=lane&15], j=0..7
        int idx = (b - 3277) * 256 + threadIdx.x;        // 61440 threads
        int j = idx & 7, lane = (idx >> 3) & 63;
        int t = idx >> 9;
        int lane16 = lane & 15, quad = lane >> 4;
        if (t < 24) {                 // B1: Bmat[k][n] = proxy[n][k] (pninv applied later)
            int kt = t >> 2, nt = t & 3;
            int k = kt * 32 + quad * 8 + j, n = nt * 16 + lane16;
            B1[idx] = f2bf(proxy[(size_t)n * FEATD + k]);
        } else if (t < 48) {          // B2: pa@proxy, Bmat[k][n] = proxy[k][n]
            int tt = t - 24, kt = tt / 12, nt = tt % 12;
            int k = kt * 32 + quad * 8 + j, n = nt * 16 + lane16;
            B2[idx - 12288] = f2bf(proxy[(size_t)k * FEATD + n]);
        } else {                      // B3: pf@gate_w^T, Bmat[k][n] = gate_w[n][k]
            int tt = t - 48, kt = tt / 12, nt = tt % 12;
            int k = kt * 32 + quad * 8 + j, n = nt * 16 + lane16;
            B3[idx - 24576] = f2bf(gate_w[(size_t)n * FEATD + k]);
        }
    } else {
        // pack edges: pe = s | (r<<16)
        int t = (b - 3517) * 256 + threadIdx.x;
        if (t < NEDGE / 4) {
            int4 s4 = *reinterpret_cast<const int4*>(src + t * 4);
            int4 r4 = *reinterpret_cast<const int4*>(rel + t * 4);
            uint4 o;
            o.x = (unsigned)s4.x | ((unsigned)r4.x << 16);
            o.y = (unsigned)s4.y | ((unsigned)r4.y << 16);
            o.z = (unsigned)s4.z | ((unsigned)r4.z << 16);
            o.w = (unsigned)s4.w | ((unsigned)r4.w << 16);
            *reinterpret_cast<uint4*>(pedge + t * 4) = o;
        }
    }
}

// ---- Layer: per-node attention aggregation (R7 shape, bf16 feats AND reln) --
// Per edge-step per lane: reln uint4 (16B) + fin uint4 (16B) — was 48B fp32.
__global__ __launch_bounds__(256) void k_layer(const unsigned int* __restrict__ pedge,
                                               const unsigned short* __restrict__ relnb,
                                               const float* __restrict__ expdot_l,
                                               const unsigned short* __restrict__ fin,
                                               unsigned short* __restrict__ fout) {
    int b = blockIdx.x;
    int lb = (b & 7) * LCHUNK + (b >> 3);
    int lane8 = threadIdx.x & 7;
    int node = lb * 32 + (threadIdx.x >> 3);
    if (node >= N_NODES) return;
    int ebase = node * DEG;
    unsigned pk[DEG];
#pragma unroll
    for (int k = 0; k < DEG; k++) pk[k] = pedge[ebase + k];
    float a0 = 0.f, a1 = 0.f, a2 = 0.f, a3 = 0.f;
    float a4 = 0.f, a5 = 0.f, a6 = 0.f, a7 = 0.f, den = 0.f;
#pragma unroll 4
    for (int k = 0; k < DEG; k++) {
        unsigned p = pk[k];
        int s = p & 0xFFFF;
        int r = p >> 16;
        float ex = expdot_l[r];
        uint4 tu = *reinterpret_cast<const uint4*>(relnb + (size_t)r * 64 + lane8 * 8);
        float t0 = lo16(tu.x), t1e = hi16(tu.x), t2 = lo16(tu.y), t3 = hi16(tu.y);
        float t4 = lo16(tu.z), t5 = hi16(tu.z), t6 = lo16(tu.w), t7 = hi16(tu.w);
        uint4 u = *reinterpret_cast<const uint4*>(fin + (size_t)s * 64 + lane8 * 8);
        float n0 = lo16(u.x), n1 = hi16(u.x), n2 = lo16(u.y), n3 = hi16(u.y);
        float n4 = lo16(u.z), n5 = hi16(u.z), n6 = lo16(u.w), n7 = hi16(u.w);
        float pd = t0 * n0 + t1e * n1 + t2 * n2 + t3 * n3
                 + t4 * n4 + t5 * n5 + t6 * n6 + t7 * n7;
        pd += __shfl_xor(pd, 1); pd += __shfl_xor(pd, 2); pd += __shfl_xor(pd, 4);
        float tw = -2.f * pd * ex;          // acc += ex*(nv - 2*dot*tv)
        a0 = fmaf(ex, n0, fmaf(tw, t0, a0));
        a1 = fmaf(ex, n1, fmaf(tw, t1e, a1));
        a2 = fmaf(ex, n2, fmaf(tw, t2, a2));
        a3 = fmaf(ex, n3, fmaf(tw, t3, a3));
        a4 = fmaf(ex, n4, fmaf(tw, t4, a4));
        a5 = fmaf(ex, n5, fmaf(tw, t5, a5));
        a6 = fmaf(ex, n6, fmaf(tw, t6, a6));
        a7 = fmaf(ex, n7, fmaf(tw, t7, a7));
        den += ex;
    }
    float id = 1.f / den;
    uint4 w;
    w.x = (unsigned)f2bf(fast_tanh(a0 * id)) | ((unsigned)f2bf(fast_tanh(a1 * id)) << 16);
    w.y = (unsigned)f2bf(fast_tanh(a2 * id)) | ((unsigned)f2bf(fast_tanh(a3 * id)) << 16);
    w.z = (unsigned)f2bf(fast_tanh(a4 * id)) | ((unsigned)f2bf(fast_tanh(a5 * id)) << 16);
    w.w = (unsigned)f2bf(fast_tanh(a6 * id)) | ((unsigned)f2bf(fast_tanh(a7 * id)) << 16);
    *reinterpret_cast<uint4*>(fout + (size_t)node * 64 + lane8 * 8) = w;
}

// ---- GATE (R11 body; lgkm-only waits instead of full fences) ----------------
__global__ __launch_bounds__(256) void k_gate(const unsigned short* __restrict__ fin0,
                                              const unsigned short* __restrict__ fin1,
                                              const unsigned short* __restrict__ fin2,
                                              const unsigned short* __restrict__ B1,
                                              const unsigned short* __restrict__ B2,
                                              const unsigned short* __restrict__ B3,
                                              const float* __restrict__ pninv,
                                              const float* __restrict__ gate_b,
                                              float* __restrict__ dout) {
    __shared__ unsigned short lds[4][16 * LSTR];
    int wv = threadIdx.x >> 6, lane = threadIdx.x & 63;
    int lb = (blockIdx.x & 7) * GCHUNK + (blockIdx.x >> 3);   // 0..783
    int tile = lb * 4 + wv;
    if (tile > NTILES - 1) tile = NTILES - 1;  // dup work, identical writes
    int row0 = tile * 16, lane16 = lane & 15, quad = lane >> 4;
    unsigned short* L = lds[wv];
    const unsigned short* fsel[3] = {fin0, fin1, fin2};

    // o in C-layout (rows quad*4+r, col nt*16+lane16) — independent, issue early
    float oreg[12][4];
#pragma unroll
    for (int nt = 0; nt < 12; nt++) {
        const unsigned short* f = fsel[nt >> 2];
#pragma unroll
        for (int r = 0; r < 4; r++)
            oreg[nt][r] = bf2f(f[(size_t)(row0 + quad * 4 + r) * 64 + (nt & 3) * 16 + lane16]);
    }

    // af: direct 16B bf16 A-fragment loads; sumsq via cvt
    bf16x8 af[6];
    float ss = 0.f;
#pragma unroll
    for (int kt = 0; kt < 6; kt++) {
        const unsigned short* f = fsel[kt >> 1];
        bf16x8 a = *reinterpret_cast<const bf16x8*>(f + (size_t)(row0 + lane16) * 64 + (kt & 1) * 32 + quad * 8);
        af[kt] = a;
#pragma unroll
        for (int i = 0; i < 8; i++) {
            float v = bf2f((unsigned short)a[i]);
            ss = fmaf(v, v, ss);
        }
    }
    ss += __shfl_xor(ss, 16); ss += __shfl_xor(ss, 32);   // full row sumsq at lane&15
    float inv = 1.f / fmaxf(sqrtf(ss), 1e-12f);
    float pni[4];
#pragma unroll
    for (int nt = 0; nt < 4; nt++) pni[nt] = pninv[nt * 16 + lane16];
    f32x4 acc4[4];
#pragma unroll
    for (int nt = 0; nt < 4; nt++) acc4[nt] = (f32x4){0.f, 0.f, 0.f, 0.f};
#pragma unroll
    for (int kt = 0; kt < 6; kt++) {
#pragma unroll
        for (int nt = 0; nt < 4; nt++) {
            bf16x8 bfr = *reinterpret_cast<const bf16x8*>(B1 + ((size_t)(kt * 4 + nt) * 64 + lane) * 8);
            acc4[nt] = __builtin_amdgcn_mfma_f32_16x16x32_bf16(af[kt], bfr, acc4[nt], 0, 0, 0);
        }
    }
    // softmax without max-sub: logits are cosine sims in [-1,1]
#pragma unroll
    for (int r = 0; r < 4; r++) {
        int rowloc = quad * 4 + r;
        float invr = __shfl(inv, rowloc);
        float e0 = __expf(acc4[0][r] * invr * pni[0]);
        float e1 = __expf(acc4[1][r] * invr * pni[1]);
        float e2 = __expf(acc4[2][r] * invr * pni[2]);
        float e3 = __expf(acc4[3][r] * invr * pni[3]);
        float s = e0 + e1 + e2 + e3;
        s += __shfl_xor(s, 1); s += __shfl_xor(s, 2);
        s += __shfl_xor(s, 4); s += __shfl_xor(s, 8);
        float rs = 1.f / s;
        L[rowloc * LSTR + lane16]      = f2bf(e0 * rs);
        L[rowloc * LSTR + 16 + lane16] = f2bf(e1 * rs);
        L[rowloc * LSTR + 32 + lane16] = f2bf(e2 * rs);
        L[rowloc * LSTR + 48 + lane16] = f2bf(e3 * rs);
    }
    WAIT_LGKM0();   // LDS-only drain; global prefetches stay in flight

    f32x4 acc[12];
#pragma unroll
    for (int nt = 0; nt < 12; nt++) acc[nt] = (f32x4){0.f, 0.f, 0.f, 0.f};
#pragma unroll
    for (int kt = 0; kt < 2; kt++) {
        bf16x8 a = *reinterpret_cast<const bf16x8*>(L + lane16 * LSTR + kt * 32 + quad * 8);
#pragma unroll
        for (int nt = 0; nt < 12; nt++) {
            bf16x8 bfr = *reinterpret_cast<const bf16x8*>(B2 + ((size_t)(kt * 12 + nt) * 64 + lane) * 8);
            acc[nt] = __builtin_amdgcn_mfma_f32_16x16x32_bf16(a, bfr, acc[nt], 0, 0, 0);
        }
    }
    WAIT_LGKM0();   // pa ds_reads drained before pf overwrites rows
#pragma unroll
    for (int nt = 0; nt < 12; nt++) {
#pragma unroll
        for (int r = 0; r < 4; r++) {
            int rowloc = quad * 4 + r;
            L[rowloc * LSTR + nt * 16 + lane16] = f2bf(oreg[nt][r] - acc[nt][r]);
        }
    }
    WAIT_LGKM0();   // pf ds_writes drained before phase-C ds_reads

#pragma unroll
    for (int nt = 0; nt < 12; nt++) acc[nt] = (f32x4){0.f, 0.f, 0.f, 0.f};
#pragma unroll
    for (int kt = 0; kt < 6; kt++) {
        bf16x8 a = *reinterpret_cast<const bf16x8*>(L + lane16 * LSTR + kt * 32 + quad * 8);
#pragma unroll
        for (int nt = 0; nt < 12; nt++) {
            bf16x8 bfr = *reinterpret_cast<const bf16x8*>(B3 + ((size_t)(kt * 12 + nt) * 64 + lane) * 8);
            acc[nt] = __builtin_amdgcn_mfma_f32_16x16x32_bf16(a, bfr, acc[nt], 0, 0, 0);
        }
    }

#pragma unroll
    for (int nt = 0; nt < 12; nt++) {
        float bias = gate_b[nt * 16 + lane16];
#pragma unroll
        for (int r = 0; r < 4; r++) {
            int rowloc = quad * 4 + r;
            size_t idx = (size_t)(row0 + rowloc) * FEATD + nt * 16 + lane16;
            float z = acc[nt][r] + bias;
            float g = 1.f / (1.f + __expf(-z));
            float pf = bf2f(L[rowloc * LSTR + nt * 16 + lane16]);
            dout[idx] = pf + g * (oreg[nt][r] - pf);
        }
    }
}

extern "C" void kernel_launch(void* const* d_in, const int* in_sizes, int n_in,
                              void* d_out, int out_size, void* d_ws, size_t ws_size,
                              hipStream_t stream) {
    (void)in_sizes; (void)n_in; (void)out_size; (void)ws_size;
    const float* features = (const float*)d_in[0];
    const float* rel_emb  = (const float*)d_in[1];
    const float* proxy    = (const float*)d_in[2];
    const float* gate_w   = (const float*)d_in[3];
    const float* gate_b   = (const float*)d_in[4];
    const float* attn_k   = (const float*)d_in[5];
    const int*   adj      = (const int*)d_in[6];
    const int*   r_index  = (const int*)d_in[7];
    // d_in[8] (r_val) unused: positive scale cancels under l2norm; r_index[0]==arange(E).

    unsigned short* fin0  = (unsigned short*)d_ws;           // N*64 bf16
    unsigned short* fin1  = fin0 + (size_t)N_NODES * 64;     // N*64 bf16
    unsigned short* fin2  = fin1 + (size_t)N_NODES * 64;     // N*64 bf16
    unsigned short* relnb = fin2 + (size_t)N_NODES * 64;     // 500*64 bf16
    float* expdot  = (float*)(relnb + RSZ * 64);             // 2*500 fp32
    float* pninv   = expdot + 2 * RSZ;                       // 64
    unsigned short* B1 = (unsigned short*)(pninv + 64);      // 12288
    unsigned short* B2 = B1 + 12288;                         // 12288
    unsigned short* B3 = B2 + 12288;                         // 36864
    unsigned int* pedge = (unsigned int*)(B3 + 36864);       // NEDGE u32

    const int* src = adj + NEDGE;       // adj[1]
    const int* rel = r_index + NEDGE;   // r_index[1]

    k_prep  <<<dim3(4693), dim3(256), 0, stream>>>(features, rel_emb, attn_k, proxy, gate_w,
                                                   src, rel, fin0, relnb, expdot,
                                                   pninv, B1, B2, B3, pedge);
    k_layer <<<dim3(LGRID), dim3(256), 0, stream>>>(pedge, relnb, expdot,       fin0, fin1);
    k_layer <<<dim3(LGRID), dim3(256), 0, stream>>>(pedge, relnb, expdot + RSZ, fin1, fin2);
    k_gate  <<<dim3(GGRID), dim3(256), 0, stream>>>(fin0, fin1, fin2, B1, B2, B3, pninv,
                                                    gate_b, (float*)d_out);
}